// Round 3
// baseline (10436.581 us; speedup 1.0000x reference)
//
#include <hip/hip_runtime.h>

// MANN/NTM encoder, MI355X persistent kernel, round 6 (= r5 resubmit).
// r5's bench died with a container infra failure (no profile, pathological
// npz push times in the prior run). DAG re-audited: no deadlock (flag cycle
// B(t)<-A(t)<-B(t-1) grounded at t=0; pk single-buffer gated by rflag; LDS
// reuse ordered by barriers). Resubmitting with s_sleep(2) (r4-proven).
//
// Structure recap:
//  * B role (128 WGs, 1/batch): NTM memory in VGPRs; keys arrive as 4
//    coalesced partials from A (pk GEMM) -> no h/emb reads at all; softmax
//    in-block; erase/add off critical path after rflag_set.
//  * A role (32 WGs): gates GEMM h-part speculative (overlaps B of t-1);
//    emb-part prefetched for t+1; critical segment = rflag -> r-part (K=64)
//    -> epilogue (per-lane gate transcendentals) -> pk GEMM + h publish.
// Flag protocol: relaxed system atomics + s_waitcnt vmcnt(0) drain.

#define T_STEPS 256
#define BSZ     128
#define IDIM    512
#define CDIM    512
#define MW      64
#define G4      2048
#define ODIM    576

typedef unsigned short u16;
typedef unsigned int   u32;
typedef short  short8  __attribute__((ext_vector_type(8)));
typedef float  floatx4 __attribute__((ext_vector_type(4)));
typedef float  f4      __attribute__((ext_vector_type(4)));

__device__ __forceinline__ float bf2f(u16 h){ return __uint_as_float(((u32)h)<<16); }
__device__ __forceinline__ u16   f2bf(float f){ u32 u = __float_as_uint(f); return (u16)((u + 0x7fffu + ((u>>16)&1u))>>16); }
__device__ __forceinline__ float sigm(float x){ return 1.f/(1.f+__expf(-x)); }

// coherent-point (L2-bypass) data movement — no cache maintenance
__device__ __forceinline__ f4 vld4(const float* p){ return *(const volatile f4*)p; }
__device__ __forceinline__ float vldf(const float* p){ return *(const volatile float*)p; }
__device__ __forceinline__ void vstf(float* p, float v){ *(volatile float*)p = v; }
__device__ __forceinline__ void vst4(float* p, f4 v){ *(volatile f4*)p = v; }

__device__ __forceinline__ void flag_set(u32* p, u32 v){
    __hip_atomic_store(p, v, __ATOMIC_RELAXED, __HIP_MEMORY_SCOPE_SYSTEM);
}
__device__ __forceinline__ void flag_wait(u32* p, u32 v){
    while (__hip_atomic_load(p, __ATOMIC_RELAXED, __HIP_MEMORY_SCOPE_SYSTEM) < v)
        __builtin_amdgcn_s_sleep(2);
}
#define VMDRAIN() asm volatile("s_waitcnt vmcnt(0)" ::: "memory")
#define CBAR()    asm volatile("" ::: "memory")

// ---------------- prep kernels ----------------

__global__ void prep_wt(const float* __restrict__ wih, const float* __restrict__ whh,
                        const float* __restrict__ bih, const float* __restrict__ bhh,
                        u16* __restrict__ WT, float* __restrict__ biasp){
    int idx = blockIdx.x*256 + threadIdx.x;          // 136*2048 = 278528
    if (idx >= 136*G4) return;
    int j  = idx & (G4-1);
    int kg = idx >> 11;
    int ro = (j&3)*512 + (j>>2);
    u32 ohi[4], olo[4];
    #pragma unroll
    for (int p=0;p<4;p++){
        int k0 = kg*8 + p*2;
        float v0 = (k0   < 576) ? wih[ro*576 + k0  ] : whh[ro*512 + k0   - 576];
        float v1 = (k0+1 < 576) ? wih[ro*576 + k0+1] : whh[ro*512 + k0+1 - 576];
        u16 h0b = f2bf(v0), h1b = f2bf(v1);
        u16 l0b = f2bf(v0 - bf2f(h0b)), l1b = f2bf(v1 - bf2f(h1b));
        ohi[p] = (u32)h0b | ((u32)h1b<<16);
        olo[p] = (u32)l0b | ((u32)l1b<<16);
    }
    *(uint4*)&WT[(size_t)idx*16]     = make_uint4(ohi[0],ohi[1],ohi[2],ohi[3]);
    *(uint4*)&WT[(size_t)idx*16 + 8] = make_uint4(olo[0],olo[1],olo[2],olo[3]);
    if (idx < G4) biasp[j] = bih[ro] + bhh[ro];
}

// Wk2: MFMA B-fragment layout for the pk GEMM.
// entry e = ((cgrp*4 + ks)*16 + nt)*64 + lane; lane=(jl,q):
//   8 bf16 = Wkey[nt*16+jl][cgrp*128 + ks*32 + q*8 .. +7]
__global__ void prep_misc(const float* __restrict__ Wrk, const float* __restrict__ Wwk,
                          const float* __restrict__ We,  const float* __restrict__ Wa,
                          const float* __restrict__ brk, const float* __restrict__ bwk,
                          const float* __restrict__ be,  const float* __restrict__ ba,
                          const float* __restrict__ h0,  const float* __restrict__ r0,
                          u16* __restrict__ Wk2, float* __restrict__ kb,
                          float* __restrict__ hbuf, float* __restrict__ xr,
                          u32* __restrict__ hflag, u32* __restrict__ rflag){
    int idx = blockIdx.x*256 + threadIdx.x;          // grid 512*256 = 131072
    if (idx < 16384) {
        int lane = idx & 63, nt = (idx>>6)&15, ks = (idx>>10)&3, cg = idx>>12;
        int jl = lane & 15, q = lane >> 4;
        int key = nt*16 + jl;
        int d0 = cg*128 + ks*32 + q*8;
        const float* src = (key<64)? Wrk + key*512 : (key<128)? Wwk + (key-64)*512
                         : (key<192)? We + (key-128)*512 : Wa + (key-192)*512;
        u32 o[4];
        #pragma unroll
        for (int p=0;p<4;p++)
            o[p] = (u32)f2bf(src[d0+2*p]) | ((u32)f2bf(src[d0+2*p+1])<<16);
        *(uint4*)&Wk2[(size_t)idx*8] = make_uint4(o[0],o[1],o[2],o[3]);
    } else if (idx < 16640) {
        int k = idx - 16384;
        kb[k] = (k<64)? brk[k] : (k<128)? bwk[k-64] : (k<192)? be[k-128] : ba[k-192];
    } else if (idx < 82176) {
        int i = idx - 16640;
        hbuf[65536 + i] = h0[i & 511];               // slot 1 = h_{-1}
    } else if (idx < 90368) {
        int i = idx - 82176;
        xr[i] = r0[i & 63];
    } else if (idx < 91392) {
        hflag[idx - 90368] = 0u;
    } else if (idx < 93440) {
        rflag[idx - 91392] = 0u;
    }
}

// ---------------- persistent kernel ----------------

__device__ __forceinline__ short8 pack_hi(f4 a, f4 b){
    union { short8 s; u16 u[8]; } r;
    r.u[0]=f2bf(a[0]); r.u[1]=f2bf(a[1]); r.u[2]=f2bf(a[2]); r.u[3]=f2bf(a[3]);
    r.u[4]=f2bf(b[0]); r.u[5]=f2bf(b[1]); r.u[6]=f2bf(b[2]); r.u[7]=f2bf(b[3]);
    return r.s;
}
__device__ __forceinline__ void pack_hilo(f4 a, f4 b, short8& hh, short8& ll){
    union { short8 s; u16 u[8]; } H, L;
    float v[8] = {a[0],a[1],a[2],a[3],b[0],b[1],b[2],b[3]};
    #pragma unroll
    for (int i=0;i<8;i++){ u16 hb = f2bf(v[i]); H.u[i]=hb; L.u[i]=f2bf(v[i]-bf2f(hb)); }
    hh = H.s; ll = L.s;
}

// fused 2-value block reductions over 512 threads (8 waves)
__device__ __forceinline__ void blkMax2(float& va, float& vb, float* red){
    #pragma unroll
    for (int o=32;o;o>>=1){ va = fmaxf(va, __shfl_xor(va,o,64)); vb = fmaxf(vb, __shfl_xor(vb,o,64)); }
    int wv = threadIdx.x >> 6;
    if ((threadIdx.x & 63) == 0){ red[wv] = va; red[8+wv] = vb; }
    __syncthreads();
    float ra = red[0], rb = red[8];
    #pragma unroll
    for (int i=1;i<8;i++){ ra = fmaxf(ra, red[i]); rb = fmaxf(rb, red[8+i]); }
    va = ra; vb = rb;
}
__device__ __forceinline__ void blkSum2(float& va, float& vb, float* red){
    #pragma unroll
    for (int o=32;o;o>>=1){ va += __shfl_xor(va,o,64); vb += __shfl_xor(vb,o,64); }
    int wv = threadIdx.x >> 6;
    if ((threadIdx.x & 63) == 0){ red[wv] = va; red[8+wv] = vb; }
    __syncthreads();
    float ra = red[0], rb = red[8];
    #pragma unroll
    for (int i=1;i<8;i++){ ra += red[i]; rb += red[8+i]; }
    va = ra; vb = rb;
}

#define BSTEP ((size_t)(4*G4*16))

// emb-part of the gates GEMM (K=512, 2-term); wave 0 also snapshots emb to LDS
// for the a-key pk tiles. embrow already offset by q*8.
__device__ __forceinline__ void emb_part(floatx4 acc[4], const float* embrow,
                                         const u16* __restrict__ bp0,
                                         float* ebst, int jl, int q, int wv){
    #pragma unroll
    for (int tl=0;tl<4;tl++){ acc[tl][0]=0.f; acc[tl][1]=0.f; acc[tl][2]=0.f; acc[tl][3]=0.f; }
    #pragma unroll 2
    for (int ks = 0; ks < 16; ++ks) {
        f4 e0 = *(const f4*)(embrow + ks*32);
        f4 e1 = *(const f4*)(embrow + ks*32 + 4);
        if (wv == 0) {
            *(f4*)&ebst[jl*516 + ks*32 + q*8]     = e0;
            *(f4*)&ebst[jl*516 + ks*32 + q*8 + 4] = e1;
        }
        short8 af = pack_hi(e0, e1);
        const u16* bks = bp0 + (size_t)ks*BSTEP;
        #pragma unroll
        for (int tl = 0; tl < 4; ++tl) {
            short8 bh = *(const short8*)(bks + tl*256);
            short8 bl = *(const short8*)(bks + tl*256 + 8);
            acc[tl] = __builtin_amdgcn_mfma_f32_16x16x32_bf16(af, bh, acc[tl], 0,0,0);
            acc[tl] = __builtin_amdgcn_mfma_f32_16x16x32_bf16(af, bl, acc[tl], 0,0,0);
        }
    }
}

__launch_bounds__(512)
__global__ void mann_persist(const float* __restrict__ embs, const u16* __restrict__ WT,
                             const float* __restrict__ biasp, const u16* __restrict__ Wk2,
                             const float* __restrict__ kbias,
                             float* __restrict__ hbuf, float* __restrict__ xr,
                             const float* __restrict__ mem0, const float* __restrict__ c0,
                             float* __restrict__ out, float* __restrict__ pkbuf,
                             u32* __restrict__ hflag, u32* __restrict__ rflag){
    __shared__ __align__(16) char smraw[140800];
    float* sp = (float*)smraw;
    const int w = blockIdx.x;
    const int tid = threadIdx.x;
    if (w >= 160) return;

    if (w < 128) {
        // ================= B role: one WG per batch, memory in VGPRs =========
        float* part = sp;            // [512][65]  read-reduction staging
        float* gsc  = sp + 33280;    // [512] reduce scratch
        float* keys = sp + 33792;    // [256] k_r | k_w | e | a
        float* red  = sp + 34048;    // [32]
        const int b = w;
        const int bgrp4 = (b>>4)*4;
        const int brow  = b & 15;
        const int n0 = tid*2;        // this thread owns memory rows n0, n0+1

        float m0[64], m1[64];
        #pragma unroll
        for (int m4=0;m4<16;m4++){
            f4 v0 = *(const f4*)(mem0 + (size_t)n0*64 + m4*4);
            f4 v1 = *(const f4*)(mem0 + (size_t)(n0+1)*64 + m4*4);
            #pragma unroll
            for (int j=0;j<4;j++){ m0[m4*4+j] = v0[j]; m1[m4*4+j] = v1[j]; }
        }

        for (int t = 0; t < T_STEPS; ++t) {
            if (tid < 4) flag_wait(&hflag[(bgrp4 + tid)*32], (u32)(t+1));
            __syncthreads();
            CBAR();
            // keys = bias + sum of 4 A-WG partials (one coalesced RT), + nonlin
            if (tid < 256) {
                const float* pb = pkbuf + ((size_t)bgrp4*16 + brow)*256 + tid;
                float kv = kbias[tid] + vldf(pb) + vldf(pb + 4096)
                         + vldf(pb + 8192) + vldf(pb + 12288);
                if (tid >= 192)      kv = tanhf(kv);
                else if (tid >= 128) kv = sigm(kv);
                keys[tid] = kv;
            }
            __syncthreads();

            // content scores for both keys from register-resident memory rows
            float s0r=0.f, s0w=0.f, s1r=0.f, s1w=0.f;
            #pragma unroll
            for (int m4=0;m4<16;m4++){
                f4 kr = *(const f4*)&keys[m4*4];
                f4 kw = *(const f4*)&keys[64 + m4*4];
                #pragma unroll
                for (int j=0;j<4;j++){
                    s0r += m0[m4*4+j]*kr[j]; s1r += m1[m4*4+j]*kr[j];
                    s0w += m0[m4*4+j]*kw[j]; s1w += m1[m4*4+j]*kw[j];
                }
            }
            float Mr = fmaxf(s0r, s1r), Mw = fmaxf(s0w, s1w);
            blkMax2(Mr, Mw, red);                       // red[0..15]
            float e0r = __expf(s0r - Mr), e1r = __expf(s1r - Mr);
            float e0w = __expf(s0w - Mw), e1w = __expf(s1w - Mw);
            float Sr = e0r + e1r, Sw = e0w + e1w;
            blkSum2(Sr, Sw, red + 16);                  // red[16..31]

            // read partials -> padded LDS tile (stride 65: conflict-free)
            float* prow = part + tid*65;
            #pragma unroll
            for (int m=0;m<64;m++) prow[m] = e0r*m0[m] + e1r*m1[m];
            __syncthreads();
            {
                int mm = tid & 63, blk = tid >> 6;
                const float* pb2 = part + (size_t)blk*64*65 + mm;
                float s = 0.f;
                #pragma unroll
                for (int r=0;r<64;r++) s += pb2[r*65];
                gsc[tid] = s;
            }
            __syncthreads();
            float rv = 0.f;
            if (tid < 64) {
                #pragma unroll
                for (int k=0;k<8;k++) rv += gsc[k*64 + tid];
                rv /= Sr;
                vstf(xr + b*MW + tid, rv);
            }
            VMDRAIN();                                  // writers are wave 0
            if (tid == 0) flag_set(&rflag[b*16], (u32)(t+1));

            // off-path: out r write + erase/add update (registers only)
            if (tid < 64)
                out[((size_t)(t*BSZ + b))*ODIM + 512 + tid] = rv;
            float iSw = 1.f / Sw;
            float w0 = e0w*iSw, w1 = e1w*iSw;
            #pragma unroll
            for (int m4=0;m4<16;m4++){
                f4 ev = *(const f4*)&keys[128 + m4*4];
                f4 av = *(const f4*)&keys[192 + m4*4];
                #pragma unroll
                for (int j=0;j<4;j++){
                    m0[m4*4+j] = m0[m4*4+j]*(1.f - w0*ev[j]) + w0*av[j];
                    m1[m4*4+j] = m1[m4*4+j]*(1.f - w1*ev[j]) + w1*av[j];
                }
            }
        }
    } else {
        // ================= A role: 32 dedicated gates-GEMM + pk WGs ==========
        float* hst   = sp;           // [16][516] staged h_{t-1}
        float* hst2p = sp + 8256;    // [16][132] h_t slice (this WG's 128 cols)
        float* ebst  = sp + 10368;   // [16][516] emb_t snapshot (for a-key pk)
        u16*   wkl   = (u16*)(sp + 18624);  // [4096][8] Wk2 slice, persistent
        const int a = w - 128, bgrp = a >> 2, cgrp = a & 3;
        const int lane = tid & 63, wv = tid >> 6, jl = lane & 15, q = lane >> 4;
        const int colbase = cgrp*512 + wv*64;
        const int bA = bgrp*16 + jl;
        const int gl = jl & 3;                     // lane's gate type (i,f,g,o)
        const u16* bp0 = WT + ((size_t)q*G4 + colbase + jl)*16;

        // persistent LDS copy of this WG's Wk2 slice (64 KB, one-time)
        for (int i = tid; i < 4096; i += 512)
            *(uint4*)&wkl[(size_t)i*8] = *(const uint4*)&Wk2[((size_t)cgrp*4096 + i)*8];

        float biasr[4];
        #pragma unroll
        for (int tl=0; tl<4; ++tl) biasr[tl] = biasp[colbase + tl*16 + jl];

        float creg[16];                            // valid on gl==0 lanes only
        #pragma unroll
        for (int tl=0; tl<4; ++tl) {
            float cv = c0[(colbase + tl*16 + jl) >> 2];
            creg[tl*4+0]=cv; creg[tl*4+1]=cv; creg[tl*4+2]=cv; creg[tl*4+3]=cv;
        }
        floatx4 acc[4];
        emb_part(acc, embs + (size_t)bA*IDIM + q*8, bp0, ebst, jl, q, wv);
        __syncthreads();                           // wkl + ebst(0) ready

        for (int t = 0; t < T_STEPS; ++t) {
            // ---- speculative: overlaps B's phase of step t-1 ----
            if (tid < 4) flag_wait(&hflag[(bgrp*4 + tid)*32], (u32)t);
            __syncthreads();
            CBAR();
            {   // stage h_{t-1}: 16 batches x 512, one volatile burst
                const float* hsrc = hbuf + ((t+1)&1)*65536 + (size_t)bgrp*16*CDIM;
                #pragma unroll
                for (int p=0;p<4;p++){
                    int idx = p*2048 + tid*4;
                    f4 v = vld4(hsrc + idx);
                    *(f4*)&hst[(idx>>9)*516 + (idx&511)] = v;
                }
            }
            __syncthreads();
            #pragma unroll 2
            for (int ks = 18; ks < 34; ++ks) {              // h-part, 3-term
                int d = (ks-18)*32 + q*8;
                f4 h0v = *(const f4*)&hst[jl*516 + d];
                f4 h1v = *(const f4*)&hst[jl*516 + d + 4];
                short8 ah, al; pack_hilo(h0v, h1v, ah, al);
                const u16* bks = bp0 + (size_t)ks*BSTEP;
                #pragma unroll
                for (int tl = 0; tl < 4; ++tl) {
                    short8 bh = *(const short8*)(bks + tl*256);
                    short8 bl = *(const short8*)(bks + tl*256 + 8);
                    acc[tl] = __builtin_amdgcn_mfma_f32_16x16x32_bf16(ah, bh, acc[tl], 0,0,0);
                    acc[tl] = __builtin_amdgcn_mfma_f32_16x16x32_bf16(al, bh, acc[tl], 0,0,0);
                    acc[tl] = __builtin_amdgcn_mfma_f32_16x16x32_bf16(ah, bl, acc[tl], 0,0,0);
                }
            }

            // ---- critical: rflag -> r-part -> epilogue -> pk + h publish ----
            if (tid < 16) flag_wait(&rflag[(bgrp*16 + tid)*16], (u32)t);
            __syncthreads();
            CBAR();
            #pragma unroll
            for (int ks = 16; ks < 18; ++ks) {               // r-part, per-lane
                const float* rr = xr + (size_t)(bgrp*16 + jl)*MW + (ks-16)*32 + q*8;
                f4 r0v = vld4(rr);
                f4 r1v = vld4(rr + 4);
                short8 ah, al; pack_hilo(r0v, r1v, ah, al);
                const u16* bks = bp0 + (size_t)ks*BSTEP;
                #pragma unroll
                for (int tl = 0; tl < 4; ++tl) {
                    short8 bh = *(const short8*)(bks + tl*256);
                    short8 bl = *(const short8*)(bks + tl*256 + 8);
                    acc[tl] = __builtin_amdgcn_mfma_f32_16x16x32_bf16(ah, bh, acc[tl], 0,0,0);
                    acc[tl] = __builtin_amdgcn_mfma_f32_16x16x32_bf16(al, bh, acc[tl], 0,0,0);
                    acc[tl] = __builtin_amdgcn_mfma_f32_16x16x32_bf16(ah, bl, acc[tl], 0,0,0);
                }
            }
            // epilogue: lane transforms its OWN gate, then quad shuffle;
            // cell state lives on gl==0 lanes only
            #pragma unroll
            for (int tl = 0; tl < 4; ++tl) {
                int j = colbase + tl*16 + jl;
                float bias = biasr[tl];
                #pragma unroll
                for (int rg = 0; rg < 4; ++rg) {
                    float gval = acc[tl][rg] + bias;
                    float tval = (gl == 2) ? tanhf(gval) : sigm(gval);
                    int base = lane & ~3;
                    float iv = __shfl(tval, base+0, 64);
                    float fv = __shfl(tval, base+1, 64);
                    float gv = __shfl(tval, base+2, 64);
                    float ov = __shfl(tval, base+3, 64);
                    if (gl == 0) {
                        float cn = fv*creg[tl*4+rg] + iv*gv;
                        creg[tl*4+rg] = cn;
                        float hn = ov*tanhf(cn);
                        int nloc = (j >> 2) - cgrp*128;
                        hst2p[(q*4+rg)*132 + nloc] = hn;
                    }
                }
            }
            __syncthreads();
            // pk: partial keys GEMM. waves 0-5: h-source tiles (keys 0..191);
            // waves 6-7: emb-source tiles (keys 192..255, the a-key).
            {
                const int nt0 = wv*2;
                const float* abase = ((nt0 < 12) ? (hst2p + jl*132)
                                                 : (ebst + jl*516 + cgrp*128)) + q*8;
                floatx4 pka = {0.f,0.f,0.f,0.f}, pkb = {0.f,0.f,0.f,0.f};
                #pragma unroll
                for (int ks = 0; ks < 4; ++ks) {
                    f4 a0 = *(const f4*)(abase + ks*32);
                    f4 a1 = *(const f4*)(abase + ks*32 + 4);
                    short8 ah, al; pack_hilo(a0, a1, ah, al);
                    const u16* wb = wkl + ((size_t)(ks*16 + nt0)*64 + lane)*8;
                    short8 b0 = *(const short8*)wb;
                    short8 b1 = *(const short8*)(wb + 64*8);
                    pka = __builtin_amdgcn_mfma_f32_16x16x32_bf16(ah, b0, pka, 0,0,0);
                    pka = __builtin_amdgcn_mfma_f32_16x16x32_bf16(al, b0, pka, 0,0,0);
                    pkb = __builtin_amdgcn_mfma_f32_16x16x32_bf16(ah, b1, pkb, 0,0,0);
                    pkb = __builtin_amdgcn_mfma_f32_16x16x32_bf16(al, b1, pkb, 0,0,0);
                }
                float* pd = pkbuf + ((size_t)a*16 + q*4)*256 + jl;
                #pragma unroll
                for (int rg = 0; rg < 4; ++rg) {
                    vstf(pd + rg*256 + nt0*16,      pka[rg]);
                    vstf(pd + rg*256 + nt0*16 + 16, pkb[rg]);
                }
            }
            {   // coalesced f4 publish of the h slice (A self-consumption)
                float* hw = hbuf + (t&1)*65536;
                int idx = tid*4;
                int brl = idx >> 7, nloc = idx & 127;
                f4 v = *(const f4*)&hst2p[brl*132 + nloc];
                vst4(hw + (size_t)(bgrp*16 + brl)*CDIM + cgrp*128 + nloc, v);
            }
            VMDRAIN();
            __syncthreads();
            if (tid == 0) flag_set(&hflag[a*32], (u32)(t+1));

            // ---- off-path: out h write + emb-part prefetch for t+1 ----
            {
                int idx = tid*4;
                int brl = idx >> 7, nloc = idx & 127;
                f4 v = *(const f4*)&hst2p[brl*132 + nloc];
                *(f4*)(out + ((size_t)(t*BSZ + bgrp*16 + brl))*ODIM + cgrp*128 + nloc) = v;
            }
            if (t + 1 < T_STEPS)
                emb_part(acc, embs + ((size_t)((t+1)*BSZ + bA))*IDIM + q*8,
                         bp0, ebst, jl, q, wv);
        }
    }
}

// ---------------- launch ----------------

#define OFF_WT     0u
#define OFF_BIASP  8912896u
#define OFF_WK2    8921088u
#define OFF_KBIAS  9183232u
#define OFF_HBUF   9184256u
#define OFF_XR     9708544u
#define OFF_PK     9741312u
#define OFF_HFLAG  10265600u
#define OFF_RFLAG  10269696u
#define WS_NEED    10277888u

extern "C" void kernel_launch(void* const* d_in, const int* in_sizes, int n_in,
                              void* d_out, int out_size, void* d_ws, size_t ws_size,
                              hipStream_t stream) {
    if (ws_size < (size_t)WS_NEED) return;

    const float* embs = (const float*)d_in[0];
    const float* w_ih = (const float*)d_in[1];
    const float* w_hh = (const float*)d_in[2];
    const float* b_ih = (const float*)d_in[3];
    const float* b_hh = (const float*)d_in[4];
    const float* h0   = (const float*)d_in[5];
    const float* c0   = (const float*)d_in[6];
    const float* r0   = (const float*)d_in[7];
    const float* mem0 = (const float*)d_in[8];
    const float* Wrk  = (const float*)d_in[9];
    const float* brk  = (const float*)d_in[10];
    const float* Wwk  = (const float*)d_in[11];
    const float* bwk  = (const float*)d_in[12];
    const float* We   = (const float*)d_in[13];
    const float* be   = (const float*)d_in[14];
    const float* Wa   = (const float*)d_in[15];
    const float* ba   = (const float*)d_in[16];

    char* ws = (char*)d_ws;
    u16*   WT    = (u16*)  (ws + OFF_WT);
    float* biasp = (float*)(ws + OFF_BIASP);
    u16*   Wk2   = (u16*)  (ws + OFF_WK2);
    float* kbias = (float*)(ws + OFF_KBIAS);
    float* hbuf  = (float*)(ws + OFF_HBUF);
    float* xrp   = (float*)(ws + OFF_XR);
    float* pkb   = (float*)(ws + OFF_PK);
    u32*   hflag = (u32*)  (ws + OFF_HFLAG);
    u32*   rflag = (u32*)  (ws + OFF_RFLAG);
    float* outp  = (float*)d_out;

    hipLaunchKernelGGL(prep_wt,   dim3(1088), dim3(256), 0, stream,
                       w_ih, w_hh, b_ih, b_hh, WT, biasp);
    hipLaunchKernelGGL(prep_misc, dim3(512),  dim3(256), 0, stream,
                       Wrk, Wwk, We, Wa, brk, bwk, be, ba, h0, r0,
                       Wk2, kbias, hbuf, xrp, hflag, rflag);

    const float* embs_c = embs; const u16* WT_c = WT; const float* biasp_c = biasp;
    const u16* Wk2_c = Wk2; const float* kbias_c = kbias;
    const float* mem0_c = mem0; const float* c0_c = c0;
    void* kargs[] = { (void*)&embs_c, (void*)&WT_c, (void*)&biasp_c, (void*)&Wk2_c,
                      (void*)&kbias_c, (void*)&hbuf, (void*)&xrp, (void*)&mem0_c,
                      (void*)&c0_c, (void*)&outp, (void*)&pkb,
                      (void*)&hflag, (void*)&rflag };
    hipLaunchCooperativeKernel((void*)mann_persist, dim3(160), dim3(512), kargs, 0, stream);
}